// Round 2
// baseline (5278.101 us; speedup 1.0000x reference)
//
#include <hip/hip_runtime.h>
#include <hip/hip_bf16.h>

#define NATOMS 16384
#define MOLS   64
#define ATOMSM 256
#define EGB    524288
#define EGNN   262144
#define HID    128
#define NH     (NATOMS*HID)

#define OFFSETC 0.009f
#define ALPHAC  1.0f
#define BETAC   0.8f
#define GAMMAC  4.85f
#define PREFC   (-138.935456f*(1.0f-1.0f/78.5f))

__device__ __forceinline__ float sigf(float x){ return 1.0f/(1.0f+__expf(-x)); }
__device__ __forceinline__ float waveRed(float v){
    v += __shfl_xor(v,32); v += __shfl_xor(v,16); v += __shfl_xor(v,8);
    v += __shfl_xor(v,4);  v += __shfl_xor(v,2);  v += __shfl_xor(v,1);
    return v;
}

// ---------------- GB part ----------------
__global__ __launch_bounds__(256) void k_gbA(
    const float* __restrict__ pos, const float* __restrict__ feat,
    const int* __restrict__ ei, float* __restrict__ Isum)
{
    int e = blockIdx.x*256 + threadIdx.x;
    if (e >= EGB) return;
    int s = ei[e], dd = ei[EGB+e];
    float dx = pos[3*s+0] - pos[3*dd+0];
    float dy = pos[3*s+1] - pos[3*dd+1];
    float dz = pos[3*s+2] - pos[3*dd+2];
    float d  = sqrtf(dx*dx+dy*dy+dz*dz + 1e-12f);
    float sr = feat[7*s+2] * (feat[7*s+1] - OFFSETC);
    float rho_i = feat[7*dd+1] - OFFSETC;
    float U = d + sr;
    if (rho_i < U){
        float L = fmaxf(rho_i, fabsf(d - sr));
        float invU = 1.0f/U, invL = 1.0f/L;
        float I = 0.5f*invL - 0.5f*invU
                + 0.125f*(d - sr*sr/d)*(invU*invU - invL*invL)
                + 0.25f*__logf(L*invU)/d;
        atomicAdd(&Isum[dd], I);
    }
}

__global__ __launch_bounds__(256) void k_gbB(
    const float* __restrict__ feat, const float* __restrict__ Isum,
    float* __restrict__ Bv, float* __restrict__ cB, float* __restrict__ gB,
    float* __restrict__ egb)
{
    int i = blockIdx.x*256 + threadIdx.x;
    if (i >= NATOMS) return;
    float q   = feat[7*i+0];
    float rad = feat[7*i+1];
    float rho = rad - OFFSETC;
    float psi = Isum[i]*rho;
    float u = psi*(ALPHAC + psi*(-BETAC + GAMMAC*psi));
    float t = tanhf(u);
    float B = 1.0f/(1.0f/rho - t/rad);
    Bv[i] = B;
    float du = ALPHAC + psi*(-2.0f*BETAC + 3.0f*GAMMAC*psi);
    cB[i] = B*B*((1.0f-t*t)/rad)*du*rho;     // dB/dpsi * dpsi/dIsum
    float Cs = 0.5f*PREFC*q*q;
    egb[i] = Cs/B;
    gB[i]  = -Cs/(B*B);
}

__global__ __launch_bounds__(256) void k_gbC(
    const float* __restrict__ pos, const float* __restrict__ feat,
    const int* __restrict__ ei, const float* __restrict__ Bv,
    float* __restrict__ egb, float* __restrict__ gdgb, float* __restrict__ gB)
{
    int e = blockIdx.x*256 + threadIdx.x;
    if (e >= EGB) return;
    int s = ei[e], dd = ei[EGB+e];
    float dx = pos[3*s+0] - pos[3*dd+0];
    float dy = pos[3*s+1] - pos[3*dd+1];
    float dz = pos[3*s+2] - pos[3*dd+2];
    float d  = sqrtf(dx*dx+dy*dy+dz*dz + 1e-12f);
    float qs = feat[7*s+0], qd = feat[7*dd+0];
    float Bs = Bv[s], Bd = Bv[dd];
    float C = 0.5f*PREFC*qd*qs;
    float P = Bd*Bs;
    float ex = __expf(-d*d/(4.0f*P));
    float f2 = d*d + P*ex;
    float f  = sqrtf(f2);
    atomicAdd(&egb[dd], C/f);
    float f3 = f2*f;
    gdgb[e] = -C*d*(1.0f - 0.25f*ex)/f3;
    float common = -C*ex*(1.0f + d*d/(4.0f*P))/(2.0f*f3);
    atomicAdd(&gB[dd], common*Bs);
    atomicAdd(&gB[s],  common*Bd);
}

__global__ __launch_bounds__(256) void k_gbE(
    const float* __restrict__ pos, const float* __restrict__ feat,
    const int* __restrict__ ei, const float* __restrict__ gB, const float* __restrict__ cB,
    const float* __restrict__ gdgb, float* __restrict__ grad)
{
    int e = blockIdx.x*256 + threadIdx.x;
    if (e >= EGB) return;
    int s = ei[e], dd = ei[EGB+e];
    float dx = pos[3*s+0] - pos[3*dd+0];
    float dy = pos[3*s+1] - pos[3*dd+1];
    float dz = pos[3*s+2] - pos[3*dd+2];
    float d  = sqrtf(dx*dx+dy*dy+dz*dz + 1e-12f);
    float sr = feat[7*s+2] * (feat[7*s+1] - OFFSETC);
    float rho_i = feat[7*dd+1] - OFFSETC;
    float U = d + sr;
    float gd = gdgb[e];
    if (rho_i < U){
        float a = fabsf(d - sr);
        float L, Lp;
        if (rho_i >= a){ L = rho_i; Lp = 0.0f; }
        else { L = a; Lp = (d >= sr) ? 1.0f : -1.0f; }
        float invU = 1.0f/U, invL = 1.0f/L;
        float invU2 = invU*invU, invL2 = invL*invL;
        float dIdd = -0.5f*Lp*invL2 + 0.5f*invU2
            + 0.125f*(1.0f + sr*sr/(d*d))*(invU2 - invL2)
            + 0.125f*(d - sr*sr/d)*(2.0f*Lp*invL2*invL - 2.0f*invU2*invU)
            + 0.25f*((Lp*invL - invU)/d - __logf(L*invU)/(d*d));
        gd += gB[dd]*cB[dd]*dIdd;
    }
    float c = gd/d;
    atomicAdd(&grad[3*s+0],  c*dx);
    atomicAdd(&grad[3*s+1],  c*dy);
    atomicAdd(&grad[3*s+2],  c*dz);
    atomicAdd(&grad[3*dd+0], -c*dx);
    atomicAdd(&grad[3*dd+1], -c*dy);
    atomicAdd(&grad[3*dd+2], -c*dz);
}

// ---------------- GNN part ----------------
__global__ __launch_bounds__(256) void k_dist(
    const float* __restrict__ pos, const int* __restrict__ gei,
    float* __restrict__ dgnn, int* __restrict__ cnt)
{
    int e = blockIdx.x*256 + threadIdx.x;
    if (e >= EGNN) return;
    int s = gei[e], dd = gei[EGNN+e];
    float dx = pos[3*s+0] - pos[3*dd+0];
    float dy = pos[3*s+1] - pos[3*dd+1];
    float dz = pos[3*s+2] - pos[3*dd+2];
    dgnn[e] = sqrtf(dx*dx+dy*dy+dz*dz + 1e-12f);
    atomicAdd(&cnt[dd], 1);
}

__global__ __launch_bounds__(256) void k_l1_fwd(
    const float* __restrict__ feat, const int* __restrict__ gei,
    const float* __restrict__ dgnn, const float* __restrict__ A1,
    const float* __restrict__ B1, float* __restrict__ Hs)
{
    int gid = blockIdx.x*256 + threadIdx.x;
    int e = gid >> 7, k = gid & 127;
    int src = gei[e], dst = gei[EGNN+e];
    float d = dgnn[e];
    float a = feat[7*src+0]*A1[k]       + feat[7*src+1]*A1[HID+k]
            + feat[7*dst+0]*A1[2*HID+k] + feat[7*dst+1]*A1[3*HID+k]
            + d*A1[4*HID+k] + B1[k];
    float h = a*sigf(a);
    atomicAdd(&Hs[dst*HID+k], h);
}

__global__ __launch_bounds__(256) void k_node_fwd(
    const float* __restrict__ Hs, const int* __restrict__ cnt,
    const float* __restrict__ C, const float* __restrict__ D,
    float* __restrict__ z, float* __restrict__ x)
{
    int gid = blockIdx.x*256 + threadIdx.x;
    int i = gid >> 7, k = gid & 127;
    if (i >= NATOMS) return;
    float acc = (float)cnt[i] * D[k];
    const float* h = Hs + i*HID;
    for (int j0=0;j0<HID;j0+=4){
        float4 h4 = *(const float4*)(h + j0);
        acc += h4.x*C[(j0+0)*HID+k] + h4.y*C[(j0+1)*HID+k]
             + h4.z*C[(j0+2)*HID+k] + h4.w*C[(j0+3)*HID+k];
    }
    z[i*HID+k] = acc;
    x[i*HID+k] = acc*sigf(acc);
}

// layer-2 forward: per-edge a = [x[src],x[dst],d]@A + b, h=silu, scatter into Hs
__global__ __launch_bounds__(256) void k_edge_fwd2(
    const int* __restrict__ gei, const float* __restrict__ dgnn,
    const float* __restrict__ xin, const float* __restrict__ A,
    const float* __restrict__ Bb, float* __restrict__ Hs)
{
    int tid = threadIdx.x;
    int k = tid & 127, half = tid >> 7;
    int e0 = blockIdx.x * 16;
    int srcs[8], dsts[8]; float acc[8];
    float wd = A[256*HID+k], bk = Bb[k];
#pragma unroll
    for (int t=0;t<8;t++){
        int e = e0 + half + 2*t;
        srcs[t] = gei[e]; dsts[t] = gei[EGNN+e];
        acc[t] = dgnn[e]*wd + bk;
    }
    for (int j0=0;j0<HID;j0+=4){
        float wa0=A[(j0+0)*HID+k], wa1=A[(j0+1)*HID+k], wa2=A[(j0+2)*HID+k], wa3=A[(j0+3)*HID+k];
        float wb0=A[(HID+j0+0)*HID+k], wb1=A[(HID+j0+1)*HID+k], wb2=A[(HID+j0+2)*HID+k], wb3=A[(HID+j0+3)*HID+k];
#pragma unroll
        for (int t=0;t<8;t++){
            float4 xs = *(const float4*)(xin + srcs[t]*HID + j0);
            float4 xd = *(const float4*)(xin + dsts[t]*HID + j0);
            acc[t] += xs.x*wa0 + xs.y*wa1 + xs.z*wa2 + xs.w*wa3
                    + xd.x*wb0 + xd.y*wb1 + xd.z*wb2 + xd.w*wb3;
        }
    }
#pragma unroll
    for (int t=0;t<8;t++){
        float a = acc[t];
        atomicAdd(&Hs[dsts[t]*HID+k], a*sigf(a));
    }
}

// layer-3 forward + backward fused
__global__ __launch_bounds__(256) void k_l3_fwdbwd(
    const int* __restrict__ gei, const float* __restrict__ dgnn,
    const float* __restrict__ x2, const float* __restrict__ A,
    const float* __restrict__ Bb, const float* __restrict__ C3,
    const float* __restrict__ D3,
    float* __restrict__ x3, float* __restrict__ gx2, float* __restrict__ gdg)
{
    __shared__ float ga[16][HID];
    __shared__ float redS[4][8];
    __shared__ float redG[4][8];
    int tid = threadIdx.x;
    int k = tid & 127, half = tid >> 7;
    int wave = tid >> 6, lane = tid & 63;
    int e0 = blockIdx.x * 16;
    int srcs[8], dsts[8]; float acc[8];
    float wd = A[256*HID+k], bk = Bb[k], c3 = C3[k];
#pragma unroll
    for (int t=0;t<8;t++){
        int e = e0 + half + 2*t;
        srcs[t] = gei[e]; dsts[t] = gei[EGNN+e];
        acc[t] = dgnn[e]*wd + bk;
    }
    for (int j0=0;j0<HID;j0+=4){
        float wa0=A[(j0+0)*HID+k], wa1=A[(j0+1)*HID+k], wa2=A[(j0+2)*HID+k], wa3=A[(j0+3)*HID+k];
        float wb0=A[(HID+j0+0)*HID+k], wb1=A[(HID+j0+1)*HID+k], wb2=A[(HID+j0+2)*HID+k], wb3=A[(HID+j0+3)*HID+k];
#pragma unroll
        for (int t=0;t<8;t++){
            float4 xs = *(const float4*)(x2 + srcs[t]*HID + j0);
            float4 xd = *(const float4*)(x2 + dsts[t]*HID + j0);
            acc[t] += xs.x*wa0 + xs.y*wa1 + xs.z*wa2 + xs.w*wa3
                    + xd.x*wb0 + xd.y*wb1 + xd.z*wb2 + xd.w*wb3;
        }
    }
#pragma unroll
    for (int t=0;t<8;t++){
        float a = acc[t];
        float sg = sigf(a);
        float h = a*sg;
        float ds = sg*(1.0f + a*(1.0f - sg));
        float gv = c3*ds;
        ga[half+2*t][k] = gv;
        float sp = waveRed(h*c3);
        float gp = waveRed(gv*wd);
        if (lane==0){ redS[wave][t]=sp; redG[wave][t]=gp; }
    }
    __syncthreads();
    if (tid < 16){
        int h = tid>>3, t = tid&7;
        int e = e0 + h + 2*t;
        float s = redS[2*h][t] + redS[2*h+1][t] + D3[0];
        float g = redG[2*h][t] + redG[2*h+1][t];
        atomicAdd(&x3[gei[EGNN+e]], s);
        gdg[e] = g;
    }
    __syncthreads();
    // phase 2: gm_j = sum_k ga[k]*A[j][k], scatter into gx2
    int j = tid;
    const float* row = A + j*HID;
#pragma unroll 1
    for (int t2=0;t2<16;t2++){
        float gm = 0.0f;
        for (int k0=0;k0<HID;k0+=4){
            float4 g4 = *(const float4*)&ga[t2][k0];
            float4 w4 = *(const float4*)(row + k0);
            gm += g4.x*w4.x + g4.y*w4.y + g4.z*w4.z + g4.w*w4.w;
        }
        int e = e0 + t2;
        int node = (j < HID) ? gei[e] : gei[EGNN+e];
        atomicAdd(&gx2[node*HID + (j&127)], gm);
    }
}

// layer-2 backward
__global__ __launch_bounds__(256) void k_l2_bwd(
    const int* __restrict__ gei, const float* __restrict__ dgnn,
    const float* __restrict__ x1, const float* __restrict__ A,
    const float* __restrict__ Bb, const float* __restrict__ gH,
    float* __restrict__ gx1, float* __restrict__ gdg)
{
    __shared__ float ga[16][HID];
    __shared__ float redG[4][8];
    int tid = threadIdx.x;
    int k = tid & 127, half = tid >> 7;
    int wave = tid >> 6, lane = tid & 63;
    int e0 = blockIdx.x * 16;
    int srcs[8], dsts[8]; float acc[8];
    float wd = A[256*HID+k], bk = Bb[k];
#pragma unroll
    for (int t=0;t<8;t++){
        int e = e0 + half + 2*t;
        srcs[t] = gei[e]; dsts[t] = gei[EGNN+e];
        acc[t] = dgnn[e]*wd + bk;
    }
    for (int j0=0;j0<HID;j0+=4){
        float wa0=A[(j0+0)*HID+k], wa1=A[(j0+1)*HID+k], wa2=A[(j0+2)*HID+k], wa3=A[(j0+3)*HID+k];
        float wb0=A[(HID+j0+0)*HID+k], wb1=A[(HID+j0+1)*HID+k], wb2=A[(HID+j0+2)*HID+k], wb3=A[(HID+j0+3)*HID+k];
#pragma unroll
        for (int t=0;t<8;t++){
            float4 xs = *(const float4*)(x1 + srcs[t]*HID + j0);
            float4 xd = *(const float4*)(x1 + dsts[t]*HID + j0);
            acc[t] += xs.x*wa0 + xs.y*wa1 + xs.z*wa2 + xs.w*wa3
                    + xd.x*wb0 + xd.y*wb1 + xd.z*wb2 + xd.w*wb3;
        }
    }
#pragma unroll
    for (int t=0;t<8;t++){
        float a = acc[t];
        float sg = sigf(a);
        float ds = sg*(1.0f + a*(1.0f - sg));
        float gv = gH[dsts[t]*HID+k]*ds;
        ga[half+2*t][k] = gv;
        float gp = waveRed(gv*wd);
        if (lane==0){ redG[wave][t]=gp; }
    }
    __syncthreads();
    if (tid < 16){
        int h = tid>>3, t = tid&7;
        int e = e0 + h + 2*t;
        gdg[e] += redG[2*h][t] + redG[2*h+1][t];
    }
    __syncthreads();
    int j = tid;
    const float* row = A + j*HID;
#pragma unroll 1
    for (int t2=0;t2<16;t2++){
        float gm = 0.0f;
        for (int k0=0;k0<HID;k0+=4){
            float4 g4 = *(const float4*)&ga[t2][k0];
            float4 w4 = *(const float4*)(row + k0);
            gm += g4.x*w4.x + g4.y*w4.y + g4.z*w4.z + g4.w*w4.w;
        }
        int e = e0 + t2;
        int node = (j < HID) ? gei[e] : gei[EGNN+e];
        atomicAdd(&gx1[node*HID + (j&127)], gm);
    }
}

__global__ __launch_bounds__(128) void k_node_bwd(
    const float* __restrict__ gx, const float* __restrict__ z,
    const float* __restrict__ C, float* __restrict__ gH)
{
    __shared__ float sh[HID];
    int i = blockIdx.x;
    int j = threadIdx.x;
    float zz = z[i*HID+j];
    float sg = sigf(zz);
    sh[j] = gx[i*HID+j]*sg*(1.0f + zz*(1.0f - sg));
    __syncthreads();
    const float* row = C + j*HID;
    float acc = 0.0f;
    for (int k0=0;k0<HID;k0+=4){
        float4 s4 = *(const float4*)&sh[k0];
        float4 w4 = *(const float4*)(row + k0);
        acc += s4.x*w4.x + s4.y*w4.y + s4.z*w4.z + s4.w*w4.w;
    }
    gH[i*HID+j] = acc;
}

__global__ __launch_bounds__(256) void k_l1_bwd(
    const float* __restrict__ feat, const int* __restrict__ gei,
    const float* __restrict__ dgnn, const float* __restrict__ A1,
    const float* __restrict__ B1, const float* __restrict__ gH,
    float* __restrict__ gdg)
{
    __shared__ float red[4];
    int gid = blockIdx.x*256 + threadIdx.x;
    int e = gid >> 7, k = gid & 127;
    int tid = threadIdx.x;
    int src = gei[e], dst = gei[EGNN+e];
    float d = dgnn[e];
    float a = feat[7*src+0]*A1[k]       + feat[7*src+1]*A1[HID+k]
            + feat[7*dst+0]*A1[2*HID+k] + feat[7*dst+1]*A1[3*HID+k]
            + d*A1[4*HID+k] + B1[k];
    float sg = sigf(a);
    float gav = gH[dst*HID+k]*sg*(1.0f + a*(1.0f - sg));
    float v = waveRed(gav * A1[4*HID+k]);
    int wave = tid>>6, lane = tid&63;
    if (lane==0) red[wave] = v;
    __syncthreads();
    if (tid==0)        gdg[e] += red[0]+red[1];
    else if (tid==128) gdg[e] += red[2]+red[3];
}

__global__ __launch_bounds__(256) void k_force_gnn(
    const float* __restrict__ pos, const int* __restrict__ gei,
    const float* __restrict__ dgnn, const float* __restrict__ gdg,
    float* __restrict__ grad)
{
    int e = blockIdx.x*256 + threadIdx.x;
    if (e >= EGNN) return;
    int s = gei[e], dd = gei[EGNN+e];
    float dx = pos[3*s+0] - pos[3*dd+0];
    float dy = pos[3*s+1] - pos[3*dd+1];
    float dz = pos[3*s+2] - pos[3*dd+2];
    float c = gdg[e]/dgnn[e];
    atomicAdd(&grad[3*s+0],  c*dx);
    atomicAdd(&grad[3*s+1],  c*dy);
    atomicAdd(&grad[3*s+2],  c*dz);
    atomicAdd(&grad[3*dd+0], -c*dx);
    atomicAdd(&grad[3*dd+1], -c*dy);
    atomicAdd(&grad[3*dd+2], -c*dz);
}

__global__ __launch_bounds__(256) void k_final(
    const float* __restrict__ egb, const float* __restrict__ x3,
    const float* __restrict__ grad, float* __restrict__ out)
{
    __shared__ float red[4];
    int m = blockIdx.x, tid = threadIdx.x;
    int i = m*ATOMSM + tid;
    float en = egb[i] + x3[i];
    float v = waveRed(en);
    int wave = tid>>6, lane = tid&63;
    if (lane==0) red[wave] = v;
    __syncthreads();
    if (tid==0) out[m] = red[0]+red[1]+red[2]+red[3];
    float* f = out + MOLS;
    f[3*i+0] = -grad[3*i+0];
    f[3*i+1] = -grad[3*i+1];
    f[3*i+2] = -grad[3*i+2];
}

extern "C" void kernel_launch(void* const* d_in, const int* in_sizes, int n_in,
                              void* d_out, int out_size, void* d_ws, size_t ws_size,
                              hipStream_t stream)
{
    const float* pos  = (const float*)d_in[0];
    const float* feat = (const float*)d_in[1];
    const int* ei  = (const int*)d_in[3];
    const int* gei = (const int*)d_in[4];
    // weights directly from inputs (fp32 row-major per reference)
    const float* A1f = (const float*)d_in[5];  const float* B1f = (const float*)d_in[6];
    const float* C1f = (const float*)d_in[7];  const float* D1f = (const float*)d_in[8];
    const float* A2f = (const float*)d_in[9];  const float* B2f = (const float*)d_in[10];
    const float* C2f = (const float*)d_in[11]; const float* D2f = (const float*)d_in[12];
    const float* A3f = (const float*)d_in[13]; const float* B3f = (const float*)d_in[14];
    const float* C3f = (const float*)d_in[15]; const float* D3f = (const float*)d_in[16];

    float* w = (float*)d_ws;
    size_t off = 0;
    auto nxt = [&](size_t n)->float*{ float* p = w + off; off += (n + 255) & ~(size_t)255; return p; };
    float* Isum = nxt(NATOMS); float* Bv = nxt(NATOMS); float* cB = nxt(NATOMS);
    float* gB = nxt(NATOMS); float* egb = nxt(NATOMS); float* x3 = nxt(NATOMS);
    int*   cnt = (int*)nxt(NATOMS);
    float* dgnn = nxt(EGNN); float* gdgnn = nxt(EGNN); float* gdgb = nxt(EGB);
    float* grad = nxt(3*NATOMS);
    float* z1 = nxt(NH); float* x1 = nxt(NH); float* z2 = nxt(NH); float* x2 = nxt(NH);
    float* Hs1 = nxt(NH); float* Hs2 = nxt(NH);
    float* gx2 = Hs1;   // reuse (free after first k_node_fwd)
    float* gH  = Hs2;   // reuse (free after second k_node_fwd)
    float* gx1 = x2;    // reuse (free after k_l3_fwdbwd)

    hipMemsetAsync(Isum, 0, NATOMS*sizeof(float), stream);
    hipMemsetAsync(x3,   0, NATOMS*sizeof(float), stream);
    hipMemsetAsync(cnt,  0, NATOMS*sizeof(int), stream);
    hipMemsetAsync(grad, 0, 3*NATOMS*sizeof(float), stream);
    hipMemsetAsync(Hs1,  0, (size_t)NH*sizeof(float), stream);
    hipMemsetAsync(Hs2,  0, (size_t)NH*sizeof(float), stream);

    // GB energies + backward
    k_gbA<<<EGB/256,256,0,stream>>>(pos, feat, ei, Isum);
    k_gbB<<<NATOMS/256,256,0,stream>>>(feat, Isum, Bv, cB, gB, egb);
    k_gbC<<<EGB/256,256,0,stream>>>(pos, feat, ei, Bv, egb, gdgb, gB);
    k_gbE<<<EGB/256,256,0,stream>>>(pos, feat, ei, gB, cB, gdgb, grad);

    // GNN forward
    k_dist<<<EGNN/256,256,0,stream>>>(pos, gei, dgnn, cnt);
    k_l1_fwd<<<(EGNN*HID)/256,256,0,stream>>>(feat, gei, dgnn, A1f, B1f, Hs1);
    k_node_fwd<<<(NATOMS*HID)/256,256,0,stream>>>(Hs1, cnt, C1f, D1f, z1, x1);
    k_edge_fwd2<<<EGNN/16,256,0,stream>>>(gei, dgnn, x1, A2f, B2f, Hs2);
    k_node_fwd<<<(NATOMS*HID)/256,256,0,stream>>>(Hs2, cnt, C2f, D2f, z2, x2);
    hipMemsetAsync(gx2, 0, (size_t)NH*sizeof(float), stream);

    // layer 3 fwd+bwd, then backward chain
    k_l3_fwdbwd<<<EGNN/16,256,0,stream>>>(gei, dgnn, x2, A3f, B3f, C3f, D3f, x3, gx2, gdgnn);
    hipMemsetAsync(gx1, 0, (size_t)NH*sizeof(float), stream);   // gx1 aliases x2 (now free)
    k_node_bwd<<<NATOMS,128,0,stream>>>(gx2, z2, C2f, gH);
    k_l2_bwd<<<EGNN/16,256,0,stream>>>(gei, dgnn, x1, A2f, B2f, gH, gx1, gdgnn);
    k_node_bwd<<<NATOMS,128,0,stream>>>(gx1, z1, C1f, gH);
    k_l1_bwd<<<(EGNN*HID)/256,256,0,stream>>>(feat, gei, dgnn, A1f, B1f, gH, gdgnn);
    k_force_gnn<<<EGNN/256,256,0,stream>>>(pos, gei, dgnn, gdgnn, grad);

    k_final<<<MOLS,256,0,stream>>>(egb, x3, grad, (float*)d_out);
}

// Round 3
// 1394.490 us; speedup vs baseline: 3.7850x; 3.7850x over previous
//
#include <hip/hip_runtime.h>
#include <hip/hip_bf16.h>

#define NATOMS 16384
#define MOLS   64
#define ATOMSM 256
#define EGB    524288
#define EGNN   262144
#define HID    128
#define NH     (NATOMS*HID)

#define OFFSETC 0.009f
#define ALPHAC  1.0f
#define BETAC   0.8f
#define GAMMAC  4.85f
#define PREFC   (-138.935456f*(1.0f-1.0f/78.5f))

__device__ __forceinline__ float sigf(float x){ return 1.0f/(1.0f+__expf(-x)); }
__device__ __forceinline__ float waveRed(float v){
    v += __shfl_xor(v,32); v += __shfl_xor(v,16); v += __shfl_xor(v,8);
    v += __shfl_xor(v,4);  v += __shfl_xor(v,2);  v += __shfl_xor(v,1);
    return v;
}

// ---------------- GB part (unchanged from passing round) ----------------
__global__ __launch_bounds__(256) void k_gbA(
    const float* __restrict__ pos, const float* __restrict__ feat,
    const int* __restrict__ ei, float* __restrict__ Isum)
{
    int e = blockIdx.x*256 + threadIdx.x;
    if (e >= EGB) return;
    int s = ei[e], dd = ei[EGB+e];
    float dx = pos[3*s+0] - pos[3*dd+0];
    float dy = pos[3*s+1] - pos[3*dd+1];
    float dz = pos[3*s+2] - pos[3*dd+2];
    float d  = sqrtf(dx*dx+dy*dy+dz*dz + 1e-12f);
    float sr = feat[7*s+2] * (feat[7*s+1] - OFFSETC);
    float rho_i = feat[7*dd+1] - OFFSETC;
    float U = d + sr;
    if (rho_i < U){
        float L = fmaxf(rho_i, fabsf(d - sr));
        float invU = 1.0f/U, invL = 1.0f/L;
        float I = 0.5f*invL - 0.5f*invU
                + 0.125f*(d - sr*sr/d)*(invU*invU - invL*invL)
                + 0.25f*__logf(L*invU)/d;
        atomicAdd(&Isum[dd], I);
    }
}

__global__ __launch_bounds__(256) void k_gbB(
    const float* __restrict__ feat, const float* __restrict__ Isum,
    float* __restrict__ Bv, float* __restrict__ cB, float* __restrict__ gB,
    float* __restrict__ egb)
{
    int i = blockIdx.x*256 + threadIdx.x;
    if (i >= NATOMS) return;
    float q   = feat[7*i+0];
    float rad = feat[7*i+1];
    float rho = rad - OFFSETC;
    float psi = Isum[i]*rho;
    float u = psi*(ALPHAC + psi*(-BETAC + GAMMAC*psi));
    float t = tanhf(u);
    float B = 1.0f/(1.0f/rho - t/rad);
    Bv[i] = B;
    float du = ALPHAC + psi*(-2.0f*BETAC + 3.0f*GAMMAC*psi);
    cB[i] = B*B*((1.0f-t*t)/rad)*du*rho;
    float Cs = 0.5f*PREFC*q*q;
    egb[i] = Cs/B;
    gB[i]  = -Cs/(B*B);
}

__global__ __launch_bounds__(256) void k_gbC(
    const float* __restrict__ pos, const float* __restrict__ feat,
    const int* __restrict__ ei, const float* __restrict__ Bv,
    float* __restrict__ egb, float* __restrict__ gdgb, float* __restrict__ gB)
{
    int e = blockIdx.x*256 + threadIdx.x;
    if (e >= EGB) return;
    int s = ei[e], dd = ei[EGB+e];
    float dx = pos[3*s+0] - pos[3*dd+0];
    float dy = pos[3*s+1] - pos[3*dd+1];
    float dz = pos[3*s+2] - pos[3*dd+2];
    float d  = sqrtf(dx*dx+dy*dy+dz*dz + 1e-12f);
    float qs = feat[7*s+0], qd = feat[7*dd+0];
    float Bs = Bv[s], Bd = Bv[dd];
    float C = 0.5f*PREFC*qd*qs;
    float P = Bd*Bs;
    float ex = __expf(-d*d/(4.0f*P));
    float f2 = d*d + P*ex;
    float f  = sqrtf(f2);
    atomicAdd(&egb[dd], C/f);
    float f3 = f2*f;
    gdgb[e] = -C*d*(1.0f - 0.25f*ex)/f3;
    float common = -C*ex*(1.0f + d*d/(4.0f*P))/(2.0f*f3);
    atomicAdd(&gB[dd], common*Bs);
    atomicAdd(&gB[s],  common*Bd);
}

__global__ __launch_bounds__(256) void k_gbE(
    const float* __restrict__ pos, const float* __restrict__ feat,
    const int* __restrict__ ei, const float* __restrict__ gB, const float* __restrict__ cB,
    const float* __restrict__ gdgb, float* __restrict__ grad)
{
    int e = blockIdx.x*256 + threadIdx.x;
    if (e >= EGB) return;
    int s = ei[e], dd = ei[EGB+e];
    float dx = pos[3*s+0] - pos[3*dd+0];
    float dy = pos[3*s+1] - pos[3*dd+1];
    float dz = pos[3*s+2] - pos[3*dd+2];
    float d  = sqrtf(dx*dx+dy*dy+dz*dz + 1e-12f);
    float sr = feat[7*s+2] * (feat[7*s+1] - OFFSETC);
    float rho_i = feat[7*dd+1] - OFFSETC;
    float U = d + sr;
    float gd = gdgb[e];
    if (rho_i < U){
        float a = fabsf(d - sr);
        float L, Lp;
        if (rho_i >= a){ L = rho_i; Lp = 0.0f; }
        else { L = a; Lp = (d >= sr) ? 1.0f : -1.0f; }
        float invU = 1.0f/U, invL = 1.0f/L;
        float invU2 = invU*invU, invL2 = invL*invL;
        float dIdd = -0.5f*Lp*invL2 + 0.5f*invU2
            + 0.125f*(1.0f + sr*sr/(d*d))*(invU2 - invL2)
            + 0.125f*(d - sr*sr/d)*(2.0f*Lp*invL2*invL - 2.0f*invU2*invU)
            + 0.25f*((Lp*invL - invU)/d - __logf(L*invU)/(d*d));
        gd += gB[dd]*cB[dd]*dIdd;
    }
    float c = gd/d;
    atomicAdd(&grad[3*s+0],  c*dx);
    atomicAdd(&grad[3*s+1],  c*dy);
    atomicAdd(&grad[3*s+2],  c*dz);
    atomicAdd(&grad[3*dd+0], -c*dx);
    atomicAdd(&grad[3*dd+1], -c*dy);
    atomicAdd(&grad[3*dd+2], -c*dz);
}

// ---------------- GNN part ----------------
__global__ __launch_bounds__(256) void k_dist(
    const float* __restrict__ pos, const int* __restrict__ gei,
    float* __restrict__ dgnn, int* __restrict__ cnt)
{
    int e = blockIdx.x*256 + threadIdx.x;
    if (e >= EGNN) return;
    int s = gei[e], dd = gei[EGNN+e];
    float dx = pos[3*s+0] - pos[3*dd+0];
    float dy = pos[3*s+1] - pos[3*dd+1];
    float dz = pos[3*s+2] - pos[3*dd+2];
    dgnn[e] = sqrtf(dx*dx+dy*dy+dz*dz + 1e-12f);
    atomicAdd(&cnt[dd], 1);
}

// layer-1 per-node projections from 2 input features
__global__ __launch_bounds__(256) void k_uv1(
    const float* __restrict__ feat, const float* __restrict__ A1,
    float* __restrict__ u1, float* __restrict__ v1)
{
    int gid = blockIdx.x*256 + threadIdx.x;   // i*128+k
    int i = gid >> 7, k = gid & 127;
    float q = feat[7*i+0], r = feat[7*i+1];
    u1[gid] = q*A1[k]       + r*A1[HID+k];
    v1[gid] = q*A1[2*HID+k] + r*A1[3*HID+k];
}

// per-node u = x@A[0:128], v = x@A[128:256] ; 4 nodes per 128-thread block
__global__ __launch_bounds__(128) void k_uv(
    const float* __restrict__ x, const float* __restrict__ A,
    float* __restrict__ u, float* __restrict__ v)
{
    __shared__ float sx[4][HID];
    int k = threadIdx.x;
    int i0 = blockIdx.x*4;
    for (int t=0;t<4;t++) sx[t][k] = x[(i0+t)*HID+k];
    __syncthreads();
    float au0=0,au1=0,au2=0,au3=0, av0=0,av1=0,av2=0,av3=0;
    for (int j=0;j<HID;j++){
        float wa = A[j*HID+k];
        float wb = A[(HID+j)*HID+k];
        float x0=sx[0][j], x1=sx[1][j], x2=sx[2][j], x3=sx[3][j];
        au0+=x0*wa; au1+=x1*wa; au2+=x2*wa; au3+=x3*wa;
        av0+=x0*wb; av1+=x1*wb; av2+=x2*wb; av3+=x3*wb;
    }
    u[(i0+0)*HID+k]=au0; u[(i0+1)*HID+k]=au1; u[(i0+2)*HID+k]=au2; u[(i0+3)*HID+k]=au3;
    v[(i0+0)*HID+k]=av0; v[(i0+1)*HID+k]=av1; v[(i0+2)*HID+k]=av2; v[(i0+3)*HID+k]=av3;
}

// per-edge forward: a = u[src]+v[dst]+d*wd+b ; silu ; atomic scatter to Hs[dst]
__global__ __launch_bounds__(128) void k_edge_fwd(
    const int* __restrict__ gei, const float* __restrict__ dgnn,
    const float* __restrict__ u, const float* __restrict__ v,
    const float* __restrict__ wdp, const float* __restrict__ bb,
    float* __restrict__ Hs)
{
    int s = blockIdx.x, k = threadIdx.x;
    float uk = u[s*HID+k], wd = wdp[k], bk = bb[k];
    int e0 = s*16;
    int dsts[16]; float dv[16];
#pragma unroll
    for (int t=0;t<16;t++){ dsts[t]=gei[EGNN+e0+t]; dv[t]=dgnn[e0+t]; }
#pragma unroll 4
    for (int t=0;t<16;t++){
        float a = uk + v[dsts[t]*HID+k] + dv[t]*wd + bk;
        atomicAdd(&Hs[dsts[t]*HID+k], a*sigf(a));
    }
}

// per-node z = Hs@C + cnt*D ; x = silu(z) ; 4 nodes per block
__global__ __launch_bounds__(128) void k_node_fwd(
    const float* __restrict__ Hs, const int* __restrict__ cnt,
    const float* __restrict__ C, const float* __restrict__ D,
    float* __restrict__ z, float* __restrict__ x)
{
    __shared__ float sh[4][HID];
    int k = threadIdx.x;
    int i0 = blockIdx.x*4;
    for (int t=0;t<4;t++) sh[t][k] = Hs[(i0+t)*HID+k];
    __syncthreads();
    float dk = D[k];
    float a0=cnt[i0+0]*dk, a1=cnt[i0+1]*dk, a2=cnt[i0+2]*dk, a3=cnt[i0+3]*dk;
    for (int j=0;j<HID;j++){
        float c = C[j*HID+k];
        a0+=sh[0][j]*c; a1+=sh[1][j]*c; a2+=sh[2][j]*c; a3+=sh[3][j]*c;
    }
    z[(i0+0)*HID+k]=a0; x[(i0+0)*HID+k]=a0*sigf(a0);
    z[(i0+1)*HID+k]=a1; x[(i0+1)*HID+k]=a1*sigf(a1);
    z[(i0+2)*HID+k]=a2; x[(i0+2)*HID+k]=a2*sigf(a2);
    z[(i0+3)*HID+k]=a3; x[(i0+3)*HID+k]=a3*sigf(a3);
}

// layer-3 fwd+bwd fused per src node
__global__ __launch_bounds__(128) void k_edge_l3(
    const int* __restrict__ gei, const float* __restrict__ dgnn,
    const float* __restrict__ u, const float* __restrict__ v,
    const float* __restrict__ A3, const float* __restrict__ B3,
    const float* __restrict__ C3, const float* __restrict__ D3,
    float* __restrict__ x3, float* __restrict__ Gs, float* __restrict__ Gd,
    float* __restrict__ gdg)
{
    __shared__ float sE[2][16], sG[2][16];
    int s = blockIdx.x, k = threadIdx.x;
    int wave = k>>6, lane = k&63;
    float uk = u[s*HID+k], wd = A3[256*HID+k], bk = B3[k], ck = C3[k];
    int e0 = s*16;
    int dsts[16]; float dv[16];
#pragma unroll
    for (int t=0;t<16;t++){ dsts[t]=gei[EGNN+e0+t]; dv[t]=dgnn[e0+t]; }
    float gs = 0.0f;
#pragma unroll 4
    for (int t=0;t<16;t++){
        float a = uk + v[dsts[t]*HID+k] + dv[t]*wd + bk;
        float sg = sigf(a);
        float h = a*sg;
        float ds = sg*(1.0f + a*(1.0f - sg));
        float ga = ck*ds;
        gs += ga;
        atomicAdd(&Gd[dsts[t]*HID+k], ga);
        float pe = waveRed(h*ck);
        float pg = waveRed(ga*wd);
        if (lane==0){ sE[wave][t]=pe; sG[wave][t]=pg; }
    }
    Gs[s*HID+k] = gs;
    __syncthreads();
    if (k < 16){
        atomicAdd(&x3[dsts[k]], sE[0][k]+sE[1][k]+D3[0]);
        gdg[e0+k] = sG[0][k]+sG[1][k];
    }
}

// per-edge backward (layers 2): ga = gH[dst]*silu'(a); Gs(reg)+Gd(atomic); gd_e
__global__ __launch_bounds__(128) void k_edge_bwd(
    const int* __restrict__ gei, const float* __restrict__ dgnn,
    const float* __restrict__ u, const float* __restrict__ v,
    const float* __restrict__ wdp, const float* __restrict__ bb,
    const float* __restrict__ gHin,
    float* __restrict__ Gs, float* __restrict__ Gd, float* __restrict__ gdg)
{
    __shared__ float sG[2][16];
    int s = blockIdx.x, k = threadIdx.x;
    int wave=k>>6, lane=k&63;
    float uk = u[s*HID+k], wd = wdp[k], bk = bb[k];
    int e0 = s*16;
    int dsts[16]; float dv[16];
#pragma unroll
    for (int t=0;t<16;t++){ dsts[t]=gei[EGNN+e0+t]; dv[t]=dgnn[e0+t]; }
    float gs = 0.0f;
#pragma unroll 4
    for (int t=0;t<16;t++){
        float a = uk + v[dsts[t]*HID+k] + dv[t]*wd + bk;
        float sg = sigf(a);
        float ds = sg*(1.0f + a*(1.0f - sg));
        float ga = gHin[dsts[t]*HID+k]*ds;
        gs += ga;
        atomicAdd(&Gd[dsts[t]*HID+k], ga);
        float pg = waveRed(ga*wd);
        if (lane==0) sG[wave][t]=pg;
    }
    Gs[s*HID+k] = gs;
    __syncthreads();
    if (k < 16) gdg[e0+k] += sG[0][k]+sG[1][k];
}

// layer-1 backward: only gd_e needed (inputs are features, not pos-dependent)
__global__ __launch_bounds__(128) void k_edge_bwd1(
    const int* __restrict__ gei, const float* __restrict__ dgnn,
    const float* __restrict__ u, const float* __restrict__ v,
    const float* __restrict__ wdp, const float* __restrict__ bb,
    const float* __restrict__ gHin, float* __restrict__ gdg)
{
    __shared__ float sG[2][16];
    int s = blockIdx.x, k = threadIdx.x;
    int wave=k>>6, lane=k&63;
    float uk = u[s*HID+k], wd = wdp[k], bk = bb[k];
    int e0 = s*16;
    int dsts[16]; float dv[16];
#pragma unroll
    for (int t=0;t<16;t++){ dsts[t]=gei[EGNN+e0+t]; dv[t]=dgnn[e0+t]; }
#pragma unroll 4
    for (int t=0;t<16;t++){
        float a = uk + v[dsts[t]*HID+k] + dv[t]*wd + bk;
        float sg = sigf(a);
        float ds = sg*(1.0f + a*(1.0f - sg));
        float ga = gHin[dsts[t]*HID+k]*ds;
        float pg = waveRed(ga*wd);
        if (lane==0) sG[wave][t]=pg;
    }
    __syncthreads();
    if (k < 16) gdg[e0+k] += sG[0][k]+sG[1][k];
}

// fused: gx = Gs@Aaᵀ + Gd@Abᵀ ; t = gx*silu'(z) ; gH = t@Cᵀ ; 4 nodes/block
__global__ __launch_bounds__(128) void k_gx_node_bwd(
    const float* __restrict__ Gs, const float* __restrict__ Gd,
    const float* __restrict__ A, const float* __restrict__ z,
    const float* __restrict__ C, float* __restrict__ gH)
{
    __shared__ float sGs[4][HID], sGd[4][HID], sh2[4][HID];
    int j = threadIdx.x;
    int i0 = blockIdx.x*4;
    for (int t=0;t<4;t++){ sGs[t][j]=Gs[(i0+t)*HID+j]; sGd[t][j]=Gd[(i0+t)*HID+j]; }
    __syncthreads();
    float a0=0,a1=0,a2=0,a3=0;
    const float* ra = A + j*HID;
    const float* rb = A + (HID+j)*HID;
    for (int k=0;k<HID;k++){
        float wa = ra[k], wb = rb[k];
        a0 += sGs[0][k]*wa + sGd[0][k]*wb;
        a1 += sGs[1][k]*wa + sGd[1][k]*wb;
        a2 += sGs[2][k]*wa + sGd[2][k]*wb;
        a3 += sGs[3][k]*wa + sGd[3][k]*wb;
    }
    {
        float zz,sg;
        zz=z[(i0+0)*HID+j]; sg=sigf(zz); sh2[0][j]=a0*sg*(1.0f+zz*(1.0f-sg));
        zz=z[(i0+1)*HID+j]; sg=sigf(zz); sh2[1][j]=a1*sg*(1.0f+zz*(1.0f-sg));
        zz=z[(i0+2)*HID+j]; sg=sigf(zz); sh2[2][j]=a2*sg*(1.0f+zz*(1.0f-sg));
        zz=z[(i0+3)*HID+j]; sg=sigf(zz); sh2[3][j]=a3*sg*(1.0f+zz*(1.0f-sg));
    }
    __syncthreads();
    float b0=0,b1=0,b2=0,b3=0;
    const float* rc = C + j*HID;
    for (int k=0;k<HID;k++){
        float wc = rc[k];
        b0+=sh2[0][k]*wc; b1+=sh2[1][k]*wc; b2+=sh2[2][k]*wc; b3+=sh2[3][k]*wc;
    }
    gH[(i0+0)*HID+j]=b0; gH[(i0+1)*HID+j]=b1; gH[(i0+2)*HID+j]=b2; gH[(i0+3)*HID+j]=b3;
}

__global__ __launch_bounds__(256) void k_force_gnn(
    const float* __restrict__ pos, const int* __restrict__ gei,
    const float* __restrict__ dgnn, const float* __restrict__ gdg,
    float* __restrict__ grad)
{
    int e = blockIdx.x*256 + threadIdx.x;
    if (e >= EGNN) return;
    int s = gei[e], dd = gei[EGNN+e];
    float dx = pos[3*s+0] - pos[3*dd+0];
    float dy = pos[3*s+1] - pos[3*dd+1];
    float dz = pos[3*s+2] - pos[3*dd+2];
    float c = gdg[e]/dgnn[e];
    atomicAdd(&grad[3*s+0],  c*dx);
    atomicAdd(&grad[3*s+1],  c*dy);
    atomicAdd(&grad[3*s+2],  c*dz);
    atomicAdd(&grad[3*dd+0], -c*dx);
    atomicAdd(&grad[3*dd+1], -c*dy);
    atomicAdd(&grad[3*dd+2], -c*dz);
}

__global__ __launch_bounds__(256) void k_final(
    const float* __restrict__ egb, const float* __restrict__ x3,
    const float* __restrict__ grad, float* __restrict__ out)
{
    __shared__ float red[4];
    int m = blockIdx.x, tid = threadIdx.x;
    int i = m*ATOMSM + tid;
    float en = egb[i] + x3[i];
    float v = waveRed(en);
    int wave = tid>>6, lane = tid&63;
    if (lane==0) red[wave] = v;
    __syncthreads();
    if (tid==0) out[m] = red[0]+red[1]+red[2]+red[3];
    float* f = out + MOLS;
    f[3*i+0] = -grad[3*i+0];
    f[3*i+1] = -grad[3*i+1];
    f[3*i+2] = -grad[3*i+2];
}

extern "C" void kernel_launch(void* const* d_in, const int* in_sizes, int n_in,
                              void* d_out, int out_size, void* d_ws, size_t ws_size,
                              hipStream_t stream)
{
    const float* pos  = (const float*)d_in[0];
    const float* feat = (const float*)d_in[1];
    const int* ei  = (const int*)d_in[3];
    const int* gei = (const int*)d_in[4];
    const float* A1f = (const float*)d_in[5];  const float* B1f = (const float*)d_in[6];
    const float* C1f = (const float*)d_in[7];  const float* D1f = (const float*)d_in[8];
    const float* A2f = (const float*)d_in[9];  const float* B2f = (const float*)d_in[10];
    const float* C2f = (const float*)d_in[11]; const float* D2f = (const float*)d_in[12];
    const float* A3f = (const float*)d_in[13]; const float* B3f = (const float*)d_in[14];
    const float* C3f = (const float*)d_in[15]; const float* D3f = (const float*)d_in[16];

    float* w = (float*)d_ws;
    size_t off = 0;
    auto nxt = [&](size_t n)->float*{ float* p = w + off; off += (n + 255) & ~(size_t)255; return p; };
    float* Isum = nxt(NATOMS); float* Bv = nxt(NATOMS); float* cB = nxt(NATOMS);
    float* gB = nxt(NATOMS); float* egb = nxt(NATOMS); float* x3 = nxt(NATOMS);
    int*   cnt = (int*)nxt(NATOMS);
    float* dgnn = nxt(EGNN); float* gdgnn = nxt(EGNN); float* gdgb = nxt(EGB);
    float* grad = nxt(3*NATOMS);
    float* u1 = nxt(NH); float* v1 = nxt(NH); float* z1 = nxt(NH); float* x1 = nxt(NH);
    float* Hs1 = nxt(NH);
    float* u2 = nxt(NH); float* v2 = nxt(NH); float* z2 = nxt(NH); float* x2 = nxt(NH);
    float* Hs2 = nxt(NH);
    float* v3 = nxt(NH);
    // aliases (lifetimes verified):
    float* Gd3 = x1;    // x1 free after k_uv(layer2)
    float* Gs3 = Hs1;   // Hs1 free after node_fwd1
    float* u3  = Hs2;   // Hs2 free after node_fwd2
    float* gH2 = Hs2;   // u3 free after k_edge_l3
    float* Gd2 = v3;    // v3 free after k_edge_l3
    float* Gs2 = x2;    // x2 free after k_uv(layer3)
    float* gH1 = Hs1;   // Gs3 free after gx_node_bwd(layer2)

    hipMemsetAsync(Isum, 0, NATOMS*sizeof(float), stream);
    hipMemsetAsync(x3,   0, NATOMS*sizeof(float), stream);
    hipMemsetAsync(cnt,  0, NATOMS*sizeof(int), stream);
    hipMemsetAsync(grad, 0, 3*NATOMS*sizeof(float), stream);
    hipMemsetAsync(Hs1,  0, (size_t)NH*sizeof(float), stream);
    hipMemsetAsync(Hs2,  0, (size_t)NH*sizeof(float), stream);

    // GB chain
    k_gbA<<<EGB/256,256,0,stream>>>(pos, feat, ei, Isum);
    k_gbB<<<NATOMS/256,256,0,stream>>>(feat, Isum, Bv, cB, gB, egb);
    k_gbC<<<EGB/256,256,0,stream>>>(pos, feat, ei, Bv, egb, gdgb, gB);
    k_gbE<<<EGB/256,256,0,stream>>>(pos, feat, ei, gB, cB, gdgb, grad);

    // GNN forward
    k_dist<<<EGNN/256,256,0,stream>>>(pos, gei, dgnn, cnt);
    k_uv1<<<NH/256,256,0,stream>>>(feat, A1f, u1, v1);
    k_edge_fwd<<<NATOMS,128,0,stream>>>(gei, dgnn, u1, v1, A1f+4*HID, B1f, Hs1);
    k_node_fwd<<<NATOMS/4,128,0,stream>>>(Hs1, cnt, C1f, D1f, z1, x1);
    k_uv<<<NATOMS/4,128,0,stream>>>(x1, A2f, u2, v2);
    hipMemsetAsync(Gd3, 0, (size_t)NH*sizeof(float), stream);    // x1 dead now
    k_edge_fwd<<<NATOMS,128,0,stream>>>(gei, dgnn, u2, v2, A2f+256*HID, B2f, Hs2);
    k_node_fwd<<<NATOMS/4,128,0,stream>>>(Hs2, cnt, C2f, D2f, z2, x2);
    k_uv<<<NATOMS/4,128,0,stream>>>(x2, A3f, u3, v3);            // u3 aliases Hs2 (dead)

    // layer-3 fwd+bwd fused
    k_edge_l3<<<NATOMS,128,0,stream>>>(gei, dgnn, u3, v3, A3f, B3f, C3f, D3f,
                                       x3, Gs3, Gd3, gdgnn);
    hipMemsetAsync(Gd2, 0, (size_t)NH*sizeof(float), stream);    // v3 dead now

    // backward chain
    k_gx_node_bwd<<<NATOMS/4,128,0,stream>>>(Gs3, Gd3, A3f, z2, C2f, gH2);
    k_edge_bwd<<<NATOMS,128,0,stream>>>(gei, dgnn, u2, v2, A2f+256*HID, B2f, gH2,
                                        Gs2, Gd2, gdgnn);
    k_gx_node_bwd<<<NATOMS/4,128,0,stream>>>(Gs2, Gd2, A2f, z1, C1f, gH1);
    k_edge_bwd1<<<NATOMS,128,0,stream>>>(gei, dgnn, u1, v1, A1f+4*HID, B1f, gH1, gdgnn);
    k_force_gnn<<<EGNN/256,256,0,stream>>>(pos, gei, dgnn, gdgnn, grad);

    k_final<<<MOLS,256,0,stream>>>(egb, x3, grad, (float*)d_out);
}